// Round 1
// baseline (124.571 us; speedup 1.0000x reference)
//
#include <hip/hip_runtime.h>
#include <hip/hip_bf16.h>

#define DD   512
#define NH   32
#define AA   18
#define JJ   (NH*AA)     // 576
#define BB   4096

// ---------------------------------------------------------------------------
// K2: partial V[n,al,d] = sum_{e in slab} U[n,al,e] * W2[n,e,d]
//     U computed on the fly from Wv/Wa (mean-subtracted adv weights).
//     grid (4 dchunk, S eslab, 32 n), 128 threads (thread = one d).
// ---------------------------------------------------------------------------
__global__ __launch_bounds__(128) void k_partialV(
    const float* __restrict__ W2, const float* __restrict__ Wv,
    const float* __restrict__ Wa, float* __restrict__ Vp, int elen)
{
    const int tid = threadIdx.x;
    const int dchunk = blockIdx.x, es = blockIdx.y, n = blockIdx.z;
    const int d  = dchunk * 128 + tid;
    const int e0 = es * elen;

    __shared__ float us[AA * 512];   // U[n][al][e-slab], stride 512

    for (int el = tid; el < elen; el += 128) {
        float wa[AA];
        float msum = 0.f;
        #pragma unroll
        for (int a = 0; a < AA; ++a) {
            wa[a] = Wa[(size_t)(n*AA + a)*DD + e0 + el];
            msum += wa[a];
        }
        msum *= (1.0f / 18.0f);
        const float wv = Wv[(size_t)n*DD + e0 + el];
        #pragma unroll
        for (int a = 0; a < AA; ++a)
            us[a*512 + el] = wv + wa[a] - msum;
    }
    __syncthreads();

    float acc[AA];
    #pragma unroll
    for (int a = 0; a < AA; ++a) acc[a] = 0.f;

    const float* w2p = W2 + (size_t)n*DD*DD + (size_t)e0*DD + d;
    #pragma unroll 4
    for (int el = 0; el < elen; ++el) {
        const float w2 = w2p[(size_t)el * DD];
        #pragma unroll
        for (int a = 0; a < AA; ++a) acc[a] += us[a*512 + el] * w2;
    }
    #pragma unroll
    for (int a = 0; a < AA; ++a)
        Vp[(size_t)es*JJ*DD + (size_t)(n*AA + a)*DD + d] = acc[a];
}

// ---------------------------------------------------------------------------
// K3: partial M[n,al,k] = sum_{d in slab} V[n,al,d] * W1[n*512+d, k]
//     V summed from S e-slabs at staging.
//     grid (4 kchunk, S dslab, 32 n), 128 threads (thread = one k).
// ---------------------------------------------------------------------------
__global__ __launch_bounds__(128) void k_partialM(
    const float* __restrict__ W1, const float* __restrict__ Vp,
    float* __restrict__ Mp, int dlen, int S)
{
    const int tid = threadIdx.x;
    const int kchunk = blockIdx.x, ds = blockIdx.y, n = blockIdx.z;
    const int k  = kchunk * 128 + tid;
    const int d0 = ds * dlen;

    __shared__ float vs[AA * 512];

    for (int dl = tid; dl < dlen; dl += 128) {
        #pragma unroll
        for (int a = 0; a < AA; ++a) {
            float v = 0.f;
            for (int s = 0; s < S; ++s)
                v += Vp[(size_t)s*JJ*DD + (size_t)(n*AA + a)*DD + d0 + dl];
            vs[a*512 + dl] = v;
        }
    }
    __syncthreads();

    float acc[AA];
    #pragma unroll
    for (int a = 0; a < AA; ++a) acc[a] = 0.f;

    const float* w1p = W1 + ((size_t)(n*DD + d0))*DD + k;
    #pragma unroll 4
    for (int dl = 0; dl < dlen; ++dl) {
        const float w1 = w1p[(size_t)dl * DD];
        #pragma unroll
        for (int a = 0; a < AA; ++a) acc[a] += vs[a*512 + dl] * w1;
    }
    #pragma unroll
    for (int a = 0; a < AA; ++a)
        Mp[(size_t)ds*JJ*DD + (size_t)(n*AA + a)*DD + k] = acc[a];
}

// ---------------------------------------------------------------------------
// K3b: collapse M slabs: M = sum_s Mp[s]
// ---------------------------------------------------------------------------
__global__ __launch_bounds__(256) void k_sumM(
    const float* __restrict__ Mp, float* __restrict__ M, int S)
{
    const int idx = blockIdx.x * 256 + threadIdx.x;      // float4 index
    if (idx >= JJ*DD/4) return;
    float4 acc = make_float4(0.f, 0.f, 0.f, 0.f);
    for (int s = 0; s < S; ++s) {
        const float4 v = ((const float4*)(Mp + (size_t)s*JJ*DD))[idx];
        acc.x += v.x; acc.y += v.y; acc.z += v.z; acc.w += v.w;
    }
    ((float4*)M)[idx] = acc;
}

// ---------------------------------------------------------------------------
// K4: c3[j] = bv[n] + ba[j] - mean(ba[n,:]) + sum_e U[j,e]*b2[n,e]
//           + sum_d V[j,d]*b1[n*512+d].   One wave per j.
// ---------------------------------------------------------------------------
__global__ __launch_bounds__(64) void k_bias(
    const float* __restrict__ Wv, const float* __restrict__ Wa,
    const float* __restrict__ b1, const float* __restrict__ b2,
    const float* __restrict__ bv, const float* __restrict__ ba,
    const float* __restrict__ Vp, float* __restrict__ c3, int S)
{
    const int j = blockIdx.x;
    const int n = j / AA, al = j % AA;
    const int lane = threadIdx.x;

    float s = 0.f;
    for (int e = lane; e < DD; e += 64) {
        float msum = 0.f;
        #pragma unroll
        for (int a = 0; a < AA; ++a) msum += Wa[(size_t)(n*AA + a)*DD + e];
        const float u = Wv[(size_t)n*DD + e]
                      + Wa[(size_t)(n*AA + al)*DD + e]
                      - msum * (1.0f/18.0f);
        s += u * b2[(size_t)n*DD + e];
    }
    for (int d = lane; d < DD; d += 64) {
        float v = 0.f;
        for (int ss = 0; ss < S; ++ss)
            v += Vp[(size_t)ss*JJ*DD + (size_t)j*DD + d];
        s += v * b1[(size_t)n*DD + d];
    }
    for (int o = 32; o; o >>= 1) s += __shfl_xor(s, o, 64);
    if (lane == 0) {
        float bam = 0.f;
        #pragma unroll
        for (int a = 0; a < AA; ++a) bam += ba[n*AA + a];
        c3[j] = s + bv[n] + ba[j] - bam * (1.0f/18.0f);
    }
}

// ---------------------------------------------------------------------------
// K5: out[b,j] = sum_k x[b,k]*M[j,k] + c3[j]
//     4096x576x512 f32 GEMM. BM=64 BN=72 BK=64, grid (64,8)=512 blocks,
//     256 threads, 2x9 micro-tile, float4 LDS reads on pad-68 stride.
// ---------------------------------------------------------------------------
#define BM 64
#define BN 72
#define BK 64
#define LSTR 68

__global__ __launch_bounds__(256) void k_gemm(
    const float* __restrict__ X, const float* __restrict__ M,
    const float* __restrict__ c3, float* __restrict__ out)
{
    __shared__ float xs[BM * LSTR];
    __shared__ float ms[BN * LSTR];

    const int t  = threadIdx.x;
    const int b0 = blockIdx.x * BM;
    const int j0 = blockIdx.y * BN;
    const int ti = t >> 3;   // 0..31 -> rows {ti, ti+32}
    const int tc = t & 7;    // 0..7  -> cols {tc+8*jj, jj<9}

    float acc[2][9] = {};

    for (int kc = 0; kc < DD; kc += BK) {
        // stage X tile: 64 rows x 16 float4
        {
            const int r  = t >> 4;      // 0..15
            const int c4 = t & 15;
            #pragma unroll
            for (int i = 0; i < 4; ++i) {
                const int rr = r + 16*i;
                const float4 v = *(const float4*)(X + (size_t)(b0 + rr)*DD + kc + 4*c4);
                *(float4*)&xs[rr*LSTR + 4*c4] = v;
            }
        }
        // stage M tile: 72 rows x 16 float4
        for (int idx = t; idx < BN*16; idx += 256) {
            const int jr = idx >> 4, c4 = idx & 15;
            const float4 v = *(const float4*)(M + (size_t)(j0 + jr)*DD + kc + 4*c4);
            *(float4*)&ms[jr*LSTR + 4*c4] = v;
        }
        __syncthreads();

        #pragma unroll
        for (int kk = 0; kk < BK/4; ++kk) {
            float4 xv[2], mv[9];
            #pragma unroll
            for (int i = 0; i < 2; ++i)
                xv[i] = *(const float4*)&xs[(ti + 32*i)*LSTR + 4*kk];
            #pragma unroll
            for (int jj = 0; jj < 9; ++jj)
                mv[jj] = *(const float4*)&ms[(tc + 8*jj)*LSTR + 4*kk];
            #pragma unroll
            for (int i = 0; i < 2; ++i)
                #pragma unroll
                for (int jj = 0; jj < 9; ++jj) {
                    acc[i][jj] += xv[i].x * mv[jj].x;
                    acc[i][jj] += xv[i].y * mv[jj].y;
                    acc[i][jj] += xv[i].z * mv[jj].z;
                    acc[i][jj] += xv[i].w * mv[jj].w;
                }
        }
        __syncthreads();
    }

    #pragma unroll
    for (int i = 0; i < 2; ++i)
        #pragma unroll
        for (int jj = 0; jj < 9; ++jj) {
            const int r = b0 + ti + 32*i;
            const int c = j0 + tc + 8*jj;
            out[(size_t)r*JJ + c] = acc[i][jj] + c3[c];
        }
}

// ---------------------------------------------------------------------------
extern "C" void kernel_launch(void* const* d_in, const int* in_sizes, int n_in,
                              void* d_out, int out_size, void* d_ws, size_t ws_size,
                              hipStream_t stream)
{
    const float* x  = (const float*)d_in[0];
    const float* W1 = (const float*)d_in[1];
    const float* b1 = (const float*)d_in[2];
    const float* W2 = (const float*)d_in[3];
    const float* b2 = (const float*)d_in[4];
    const float* Wv = (const float*)d_in[5];
    const float* bv = (const float*)d_in[6];
    const float* Wa = (const float*)d_in[7];
    const float* ba = (const float*)d_in[8];
    float* out = (float*)d_out;
    float* ws  = (float*)d_ws;

    // adaptive slab count based on workspace size
    auto need = [](int S) -> size_t {
        return ((size_t)2*S*JJ*DD + (size_t)JJ*DD + JJ) * sizeof(float);
    };
    int S = 4;
    while (S > 1 && need(S) > ws_size) S >>= 1;
    const int elen = DD / S;

    float* Vp = ws;                        // S * J * D
    float* Mp = Vp + (size_t)S*JJ*DD;      // S * J * D
    float* Mf = Mp + (size_t)S*JJ*DD;      // J * D
    float* c3 = Mf + (size_t)JJ*DD;        // J

    k_partialV<<<dim3(4, S, NH), 128, 0, stream>>>(W2, Wv, Wa, Vp, elen);
    k_partialM<<<dim3(4, S, NH), 128, 0, stream>>>(W1, Vp, Mp, elen, S);
    k_sumM<<<dim3((JJ*DD/4 + 255)/256), 256, 0, stream>>>(Mp, Mf, S);
    k_bias<<<dim3(JJ), 64, 0, stream>>>(Wv, Wa, b1, b2, bv, ba, Vp, c3, S);
    k_gemm<<<dim3(BB/BM, JJ/BN), 256, 0, stream>>>(x, Mf, c3, out);
}

// Round 2
// 93.902 us; speedup vs baseline: 1.3266x; 1.3266x over previous
//
#include <hip/hip_runtime.h>
#include <hip/hip_bf16.h>

#define DD   512
#define NH   32
#define AA   18
#define JJ   (NH*AA)          // 576
#define BB   4096
#define JD   (JJ*DD)          // 294912

typedef short bf16x8 __attribute__((ext_vector_type(8)));
typedef float f32x4  __attribute__((ext_vector_type(4)));

static __device__ inline unsigned short f2bf(float f) {
    unsigned int x = __float_as_uint(f);
    unsigned int r = (x + 0x7fffu + ((x >> 16) & 1u)) >> 16;   // RNE
    return (unsigned short)r;
}

// ---------------------------------------------------------------------------
// K0: convert x f32 -> bf16 bits.  2M elems, 4/thread.
// ---------------------------------------------------------------------------
__global__ __launch_bounds__(256) void k_convX(
    const float* __restrict__ x, unsigned short* __restrict__ Xb)
{
    const int idx = blockIdx.x * 256 + threadIdx.x;        // float4 index
    if (idx >= BB*DD/4) return;
    const float4 v = ((const float4*)x)[idx];
    ushort4 o;
    o.x = f2bf(v.x); o.y = f2bf(v.y); o.z = f2bf(v.z); o.w = f2bf(v.w);
    ((ushort4*)Xb)[idx] = o;
}

// ---------------------------------------------------------------------------
// K1: partial V[j,d] = sum_{e in slab} U[j,e] * W2[n,e,d]
//     grid (S, 32), 256 thr, thread owns d = 2*tid (float2 W2 loads).
//     FMA-bound: per 4e x 2d: 18 ds_read_b128 broadcasts + 144 FMA.
// ---------------------------------------------------------------------------
__global__ __launch_bounds__(256) void k_partialV(
    const float* __restrict__ W2, const float* __restrict__ Wv,
    const float* __restrict__ Wa, float* __restrict__ Vp, int elen)
{
    const int t = threadIdx.x;
    const int es = blockIdx.x, n = blockIdx.y;
    const int e0 = es * elen;

    __shared__ float us[AA * DD];      // [a][el], stride elen (compact)

    for (int el = t; el < elen; el += 256) {
        float wa[AA];
        float msum = 0.f;
        #pragma unroll
        for (int a = 0; a < AA; ++a) {
            wa[a] = Wa[(size_t)(n*AA + a)*DD + e0 + el];
            msum += wa[a];
        }
        msum *= (1.0f / 18.0f);
        const float wv = Wv[(size_t)n*DD + e0 + el];
        #pragma unroll
        for (int a = 0; a < AA; ++a)
            us[a*elen + el] = wv + wa[a] - msum;
    }
    __syncthreads();

    const int d = 2 * t;
    float accx[AA] = {}, accy[AA] = {};
    const float* w2b = W2 + (size_t)n*DD*DD + (size_t)e0*DD + d;

    for (int e4 = 0; e4 < elen/4; ++e4) {
        float2 w2v[4];
        #pragma unroll
        for (int j = 0; j < 4; ++j)
            w2v[j] = *(const float2*)(w2b + (size_t)(4*e4 + j)*DD);
        #pragma unroll
        for (int a = 0; a < AA; ++a) {
            const float4 u4 = *(const float4*)(us + a*elen + 4*e4);
            accx[a] += u4.x*w2v[0].x + u4.y*w2v[1].x + u4.z*w2v[2].x + u4.w*w2v[3].x;
            accy[a] += u4.x*w2v[0].y + u4.y*w2v[1].y + u4.z*w2v[2].y + u4.w*w2v[3].y;
        }
    }
    float* vout = Vp + (size_t)es*JD + (size_t)(n*AA)*DD + d;
    #pragma unroll
    for (int a = 0; a < AA; ++a)
        *(float2*)(vout + (size_t)a*DD) = make_float2(accx[a], accy[a]);
}

// ---------------------------------------------------------------------------
// K2: partial M[j,k] = sum_{d in slab} Vsum[j,d] * W1[n*512+d, k]
//     Vsum collapsed from S slabs at staging.  Same structure as K1.
// ---------------------------------------------------------------------------
__global__ __launch_bounds__(256) void k_partialM(
    const float* __restrict__ W1, const float* __restrict__ Vp,
    float* __restrict__ Mp, int dlen, int S)
{
    const int t = threadIdx.x;
    const int ds = blockIdx.x, n = blockIdx.y;
    const int d0 = ds * dlen;

    __shared__ float vs[AA * DD];      // [a][dl], stride dlen (compact)

    for (int idx = t; idx < AA*dlen; idx += 256) {
        const int a = idx / dlen, dl = idx - a*dlen;
        float v = 0.f;
        for (int s = 0; s < S; ++s)
            v += Vp[(size_t)s*JD + (size_t)(n*AA + a)*DD + d0 + dl];
        vs[idx] = v;
    }
    __syncthreads();

    const int k = 2 * t;
    float accx[AA] = {}, accy[AA] = {};
    const float* w1b = W1 + ((size_t)(n*DD + d0))*DD + k;

    for (int d4 = 0; d4 < dlen/4; ++d4) {
        float2 w1v[4];
        #pragma unroll
        for (int j = 0; j < 4; ++j)
            w1v[j] = *(const float2*)(w1b + (size_t)(4*d4 + j)*DD);
        #pragma unroll
        for (int a = 0; a < AA; ++a) {
            const float4 v4 = *(const float4*)(vs + a*dlen + 4*d4);
            accx[a] += v4.x*w1v[0].x + v4.y*w1v[1].x + v4.z*w1v[2].x + v4.w*w1v[3].x;
            accy[a] += v4.x*w1v[0].y + v4.y*w1v[1].y + v4.z*w1v[2].y + v4.w*w1v[3].y;
        }
    }
    float* mout = Mp + (size_t)ds*JD + (size_t)(n*AA)*DD + k;
    #pragma unroll
    for (int a = 0; a < AA; ++a)
        *(float2*)(mout + (size_t)a*DD) = make_float2(accx[a], accy[a]);
}

// ---------------------------------------------------------------------------
// K3: M_bf16 = sum_s Mp[s]  (slab reduce + f32->bf16)
// ---------------------------------------------------------------------------
__global__ __launch_bounds__(256) void k_sumM(
    const float* __restrict__ Mp, unsigned short* __restrict__ Mb, int S)
{
    const int idx = blockIdx.x * 256 + threadIdx.x;   // float4 index
    if (idx >= JD/4) return;
    float4 a = make_float4(0.f, 0.f, 0.f, 0.f);
    for (int s = 0; s < S; ++s) {
        const float4 v = ((const float4*)(Mp + (size_t)s*JD))[idx];
        a.x += v.x; a.y += v.y; a.z += v.z; a.w += v.w;
    }
    ushort4 o;
    o.x = f2bf(a.x); o.y = f2bf(a.y); o.z = f2bf(a.z); o.w = f2bf(a.w);
    ((ushort4*)Mb)[idx] = o;
}

// ---------------------------------------------------------------------------
// K4: folded bias c3[j]  (one wave per j) — unchanged from round 1.
// ---------------------------------------------------------------------------
__global__ __launch_bounds__(64) void k_bias(
    const float* __restrict__ Wv, const float* __restrict__ Wa,
    const float* __restrict__ b1, const float* __restrict__ b2,
    const float* __restrict__ bv, const float* __restrict__ ba,
    const float* __restrict__ Vp, float* __restrict__ c3, int S)
{
    const int j = blockIdx.x;
    const int n = j / AA, al = j % AA;
    const int lane = threadIdx.x;

    float s = 0.f;
    for (int e = lane; e < DD; e += 64) {
        float msum = 0.f;
        #pragma unroll
        for (int a = 0; a < AA; ++a) msum += Wa[(size_t)(n*AA + a)*DD + e];
        const float u = Wv[(size_t)n*DD + e]
                      + Wa[(size_t)(n*AA + al)*DD + e]
                      - msum * (1.0f/18.0f);
        s += u * b2[(size_t)n*DD + e];
    }
    for (int d = lane; d < DD; d += 64) {
        float v = 0.f;
        for (int ss = 0; ss < S; ++ss)
            v += Vp[(size_t)ss*JD + (size_t)j*DD + d];
        s += v * b1[(size_t)n*DD + d];
    }
    for (int o = 32; o; o >>= 1) s += __shfl_xor(s, o, 64);
    if (lane == 0) {
        float bam = 0.f;
        #pragma unroll
        for (int a = 0; a < AA; ++a) bam += ba[n*AA + a];
        c3[j] = s + bv[n] + ba[j] - bam * (1.0f/18.0f);
    }
}

// ---------------------------------------------------------------------------
// K5: out[b,j] = sum_k Xb[b,k]*Mb[j,k] + c3[j]   (bf16 MFMA)
//     BM=128 BN=64 BK=64, 4 waves (2m x 2n), wave-tile 64x32 = 4x2 MFMA tiles.
//     LDS: linear rows, 16B-slot XOR swizzle slot^(row&7) on write AND read.
// ---------------------------------------------------------------------------
#define GBM 128
#define GBN 64
#define GBK 64

__global__ __launch_bounds__(256) void k_gemm(
    const unsigned short* __restrict__ Xb,   // [4096][512] bf16 bits
    const unsigned short* __restrict__ Mb,   // [576][512]  bf16 bits
    const float* __restrict__ c3, float* __restrict__ out)
{
    __shared__ __align__(16) unsigned short xs[GBM * GBK];   // 16 KB
    __shared__ __align__(16) unsigned short ms[GBN * GBK];   //  8 KB

    const int t    = threadIdx.x;
    const int w    = t >> 6;
    const int lane = t & 63;
    const int ln   = lane & 15, lg = lane >> 4;
    const int wm   = w >> 1,   wn = w & 1;
    const int b0 = blockIdx.x * GBM;
    const int j0 = blockIdx.y * GBN;

    f32x4 acc[4][2] = {};

    for (int kc = 0; kc < DD; kc += GBK) {
        // stage X tile: 1024 16B chunks, swizzled slot
        #pragma unroll
        for (int it = 0; it < 4; ++it) {
            const int chunk = it*256 + t;
            const int row = chunk >> 3, slot = chunk & 7;
            const int4 v = *(const int4*)(Xb + (size_t)(b0 + row)*DD + kc + slot*8);
            *(int4*)(xs + row*GBK + ((slot ^ (row & 7)) * 8)) = v;
        }
        // stage M tile: 512 chunks
        #pragma unroll
        for (int it = 0; it < 2; ++it) {
            const int chunk = it*256 + t;
            const int row = chunk >> 3, slot = chunk & 7;
            const int4 v = *(const int4*)(Mb + (size_t)(j0 + row)*DD + kc + slot*8);
            *(int4*)(ms + row*GBK + ((slot ^ (row & 7)) * 8)) = v;
        }
        __syncthreads();

        #pragma unroll
        for (int kk = 0; kk < 2; ++kk) {
            bf16x8 av[4], bv[2];
            #pragma unroll
            for (int mt = 0; mt < 4; ++mt) {
                const int row  = 64*wm + 16*mt + ln;
                const int slot = (4*kk + lg) ^ (row & 7);
                av[mt] = *(const bf16x8*)(xs + row*GBK + slot*8);
            }
            #pragma unroll
            for (int nt = 0; nt < 2; ++nt) {
                const int row  = 32*wn + 16*nt + ln;
                const int slot = (4*kk + lg) ^ (row & 7);
                bv[nt] = *(const bf16x8*)(ms + row*GBK + slot*8);
            }
            #pragma unroll
            for (int mt = 0; mt < 4; ++mt)
                #pragma unroll
                for (int nt = 0; nt < 2; ++nt)
                    acc[mt][nt] = __builtin_amdgcn_mfma_f32_16x16x32_bf16(
                        av[mt], bv[nt], acc[mt][nt], 0, 0, 0);
        }
        __syncthreads();
    }

    // epilogue: C/D layout col=lane&15, row=(lane>>4)*4+reg  [m89/m91]
    float c3v[2];
    #pragma unroll
    for (int nt = 0; nt < 2; ++nt) c3v[nt] = c3[j0 + 32*wn + 16*nt + ln];

    #pragma unroll
    for (int mt = 0; mt < 4; ++mt)
        #pragma unroll
        for (int nt = 0; nt < 2; ++nt) {
            const int j = j0 + 32*wn + 16*nt + ln;
            #pragma unroll
            for (int r = 0; r < 4; ++r) {
                const int b = b0 + 64*wm + 16*mt + 4*lg + r;
                out[(size_t)b*JJ + j] = acc[mt][nt][r] + c3v[nt];
            }
        }
}

// ---------------------------------------------------------------------------
extern "C" void kernel_launch(void* const* d_in, const int* in_sizes, int n_in,
                              void* d_out, int out_size, void* d_ws, size_t ws_size,
                              hipStream_t stream)
{
    const float* x  = (const float*)d_in[0];
    const float* W1 = (const float*)d_in[1];
    const float* b1 = (const float*)d_in[2];
    const float* W2 = (const float*)d_in[3];
    const float* b2 = (const float*)d_in[4];
    const float* Wv = (const float*)d_in[5];
    const float* bv = (const float*)d_in[6];
    const float* Wa = (const float*)d_in[7];
    const float* ba = (const float*)d_in[8];
    float* out = (float*)d_out;
    float* ws  = (float*)d_ws;

    auto need = [](int S) -> size_t {
        return ((size_t)2*S*JD + JJ) * sizeof(float)
             + ((size_t)JD + (size_t)BB*DD) * sizeof(unsigned short) + 256;
    };
    int S = 8;
    while (S > 1 && need(S) > ws_size) S >>= 1;

    float* Vp = ws;                                   // S*JD f32
    float* Mp = Vp + (size_t)S*JD;                    // S*JD f32
    float* c3 = Mp + (size_t)S*JD;                    // JJ f32
    unsigned short* Mb = (unsigned short*)(c3 + JJ);  // JD bf16
    unsigned short* Xb = Mb + (size_t)JD;             // BB*DD bf16

    k_convX   <<<dim3(BB*DD/4/256), 256, 0, stream>>>(x, Xb);
    k_partialV<<<dim3(S, NH), 256, 0, stream>>>(W2, Wv, Wa, Vp, DD/S);
    k_partialM<<<dim3(S, NH), 256, 0, stream>>>(W1, Vp, Mp, DD/S, S);
    k_sumM    <<<dim3((JD/4 + 255)/256), 256, 0, stream>>>(Mp, Mb, S);
    k_bias    <<<dim3(JJ), 64, 0, stream>>>(Wv, Wa, b1, b2, bv, ba, Vp, c3, S);
    k_gemm    <<<dim3(BB/GBM, JJ/GBN), 256, 0, stream>>>(Xb, Mb, c3, out);
}

// Round 4
// 52.521 us; speedup vs baseline: 2.3718x; 1.7879x over previous
//
#include <hip/hip_runtime.h>
#include <hip/hip_bf16.h>

#define DD   512
#define NH   32
#define AA   18
#define JJ   (NH*AA)          // 576
#define BB   4096
#define JD   (JJ*DD)          // 294912

typedef short bf16x8 __attribute__((ext_vector_type(8)));
typedef float f32x4  __attribute__((ext_vector_type(4)));

static __device__ inline unsigned short f2bf(float f) {
    unsigned int x = __float_as_uint(f);
    unsigned int r = (x + 0x7fffu + ((x >> 16) & 1u)) >> 16;   // RNE
    return (unsigned short)r;
}

// ---------------------------------------------------------------------------
// K0: convert x f32 -> bf16 bits.  (validated R2)
// ---------------------------------------------------------------------------
__global__ __launch_bounds__(256) void k_convX(
    const float* __restrict__ x, unsigned short* __restrict__ Xb)
{
    const int idx = blockIdx.x * 256 + threadIdx.x;        // float4 index
    if (idx >= BB*DD/4) return;
    const float4 v = ((const float4*)x)[idx];
    ushort4 o;
    o.x = f2bf(v.x); o.y = f2bf(v.y); o.z = f2bf(v.z); o.w = f2bf(v.w);
    ((ushort4*)Xb)[idx] = o;
}

// ---------------------------------------------------------------------------
// K1: Vsum[n*18+a, d] = sum_e U[n,a,e] * W2[n,e,d]
//     grid (16 d-chunks x 32 heads) = 512 blocks, 256 thr (4 waves).
//     half-wave group eg (0..7) owns e in [eg*64, eg*64+64); 32-wide d chunk.
//     LDS 54 KB -> 2 blocks/CU, 8 waves/CU.
// ---------------------------------------------------------------------------
__global__ __launch_bounds__(256) void k_V(
    const float* __restrict__ W2, const float* __restrict__ Wv,
    const float* __restrict__ Wa, float* __restrict__ Vsum)
{
    const int t  = threadIdx.x;
    const int dc = blockIdx.x;          // 0..15
    const int n  = blockIdx.y;          // 0..31

    __shared__ __align__(16) float us[AA * DD];       // 36 KB  [a][e]
    __shared__ __align__(16) float red[8 * AA * 32];  // 18 KB  [eg][a][dl]

    // stage U: thread t covers e = t and t+256
    for (int el = t; el < DD; el += 256) {
        float wa[AA]; float msum = 0.f;
        #pragma unroll
        for (int a = 0; a < AA; ++a) {
            wa[a] = Wa[(size_t)(n*AA + a)*DD + el];
            msum += wa[a];
        }
        msum *= (1.0f / 18.0f);
        const float wv = Wv[(size_t)n*DD + el];
        #pragma unroll
        for (int a = 0; a < AA; ++a) us[a*DD + el] = wv + wa[a] - msum;
    }
    __syncthreads();

    const int dl = t & 31, eg = t >> 5;          // eg 0..7
    const int d  = dc*32 + dl;
    const float* w2p = W2 + (size_t)n*DD*DD + (size_t)(eg*64)*DD + d;

    float acc[AA] = {};
    for (int e8 = 0; e8 < 8; ++e8) {
        float w[8];
        #pragma unroll
        for (int j = 0; j < 8; ++j) w[j] = w2p[(size_t)(e8*8 + j)*DD];
        const int eo = eg*64 + e8*8;
        #pragma unroll
        for (int a = 0; a < AA; ++a) {
            const float4 u0 = *(const float4*)(us + a*DD + eo);
            const float4 u1 = *(const float4*)(us + a*DD + eo + 4);
            acc[a] += u0.x*w[0] + u0.y*w[1] + u0.z*w[2] + u0.w*w[3]
                    + u1.x*w[4] + u1.y*w[5] + u1.z*w[6] + u1.w*w[7];
        }
    }

    #pragma unroll
    for (int a = 0; a < AA; ++a) red[(eg*AA + a)*32 + dl] = acc[a];
    __syncthreads();

    for (int idx = t; idx < AA*32; idx += 256) {
        const int a = idx >> 5, d2 = idx & 31;
        float v = 0.f;
        #pragma unroll
        for (int g = 0; g < 8; ++g) v += red[(g*AA + a)*32 + d2];
        Vsum[(size_t)(n*AA + a)*DD + dc*32 + d2] = v;
    }
}

// ---------------------------------------------------------------------------
// K2: M[n*18+a, k] = sum_d Vsum[n*18+a, d] * W1[n*512+d, k]  -> bf16
//     same geometry as K1.
// ---------------------------------------------------------------------------
__global__ __launch_bounds__(256) void k_M(
    const float* __restrict__ W1, const float* __restrict__ Vsum,
    unsigned short* __restrict__ Mb)
{
    const int t  = threadIdx.x;
    const int kc = blockIdx.x;          // 0..15
    const int n  = blockIdx.y;          // 0..31

    __shared__ __align__(16) float vs[AA * DD];       // 36 KB
    __shared__ __align__(16) float red[8 * AA * 32];  // 18 KB

    for (int i = t; i < AA*DD/4; i += 256)
        ((float4*)vs)[i] = ((const float4*)(Vsum + (size_t)n*AA*DD))[i];
    __syncthreads();

    const int kl = t & 31, dg = t >> 5;
    const int k  = kc*32 + kl;
    const float* w1p = W1 + ((size_t)(n*DD + dg*64))*DD + k;

    float acc[AA] = {};
    for (int d8 = 0; d8 < 8; ++d8) {
        float w[8];
        #pragma unroll
        for (int j = 0; j < 8; ++j) w[j] = w1p[(size_t)(d8*8 + j)*DD];
        const int doff = dg*64 + d8*8;
        #pragma unroll
        for (int a = 0; a < AA; ++a) {
            const float4 v0 = *(const float4*)(vs + a*DD + doff);
            const float4 v1 = *(const float4*)(vs + a*DD + doff + 4);
            acc[a] += v0.x*w[0] + v0.y*w[1] + v0.z*w[2] + v0.w*w[3]
                    + v1.x*w[4] + v1.y*w[5] + v1.z*w[6] + v1.w*w[7];
        }
    }

    #pragma unroll
    for (int a = 0; a < AA; ++a) red[(dg*AA + a)*32 + kl] = acc[a];
    __syncthreads();

    for (int idx = t; idx < AA*32; idx += 256) {
        const int a = idx >> 5, k2 = idx & 31;
        float v = 0.f;
        #pragma unroll
        for (int g = 0; g < 8; ++g) v += red[(g*AA + a)*32 + k2];
        Mb[(size_t)(n*AA + a)*DD + kc*32 + k2] = f2bf(v);
    }
}

// ---------------------------------------------------------------------------
// K3: folded bias c3[j] = bv + ba - mean(ba) + U.b2 + Vsum.b1
// ---------------------------------------------------------------------------
__global__ __launch_bounds__(64) void k_bias(
    const float* __restrict__ Wv, const float* __restrict__ Wa,
    const float* __restrict__ b1, const float* __restrict__ b2,
    const float* __restrict__ bv, const float* __restrict__ ba,
    const float* __restrict__ Vsum, float* __restrict__ c3)
{
    const int j = blockIdx.x;
    const int n = j / AA, al = j % AA;
    const int lane = threadIdx.x;

    float s = 0.f;
    for (int e = lane; e < DD; e += 64) {
        float msum = 0.f;
        #pragma unroll
        for (int a = 0; a < AA; ++a) msum += Wa[(size_t)(n*AA + a)*DD + e];
        const float u = Wv[(size_t)n*DD + e]
                      + Wa[(size_t)(n*AA + al)*DD + e]
                      - msum * (1.0f/18.0f);
        s += u * b2[(size_t)n*DD + e];
    }
    for (int d = lane; d < DD; d += 64)
        s += Vsum[(size_t)j*DD + d] * b1[(size_t)n*DD + d];
    for (int o = 32; o; o >>= 1) s += __shfl_xor(s, o, 64);
    if (lane == 0) {
        float bam = 0.f;
        #pragma unroll
        for (int a = 0; a < AA; ++a) bam += ba[n*AA + a];
        c3[j] = s + bv[n] + ba[j] - bam * (1.0f/18.0f);
    }
}

// ---------------------------------------------------------------------------
// K4: out[b,j] = sum_k Xb[b,k]*Mb[j,k] + c3[j]   (bf16 MFMA)
//     EXACT copy of the R2-validated kernel: BM=128 BN=64 BK=64, 4 waves,
//     XOR-swizzled LDS (SQ_LDS_BANK_CONFLICT == 0 measured).
// ---------------------------------------------------------------------------
#define GBM 128
#define GBN 64
#define GBK 64

__global__ __launch_bounds__(256) void k_gemm(
    const unsigned short* __restrict__ Xb,   // [4096][512] bf16 bits
    const unsigned short* __restrict__ Mb,   // [576][512]  bf16 bits
    const float* __restrict__ c3, float* __restrict__ out)
{
    __shared__ __align__(16) unsigned short xs[GBM * GBK];   // 16 KB
    __shared__ __align__(16) unsigned short ms[GBN * GBK];   //  8 KB

    const int t    = threadIdx.x;
    const int w    = t >> 6;
    const int lane = t & 63;
    const int ln   = lane & 15, lg = lane >> 4;
    const int wm   = w >> 1,   wn = w & 1;
    const int b0 = blockIdx.x * GBM;
    const int j0 = blockIdx.y * GBN;

    f32x4 acc[4][2] = {};

    for (int kc = 0; kc < DD; kc += GBK) {
        #pragma unroll
        for (int it = 0; it < 4; ++it) {
            const int chunk = it*256 + t;
            const int row = chunk >> 3, slot = chunk & 7;
            const int4 v = *(const int4*)(Xb + (size_t)(b0 + row)*DD + kc + slot*8);
            *(int4*)(xs + row*GBK + ((slot ^ (row & 7)) * 8)) = v;
        }
        #pragma unroll
        for (int it = 0; it < 2; ++it) {
            const int chunk = it*256 + t;
            const int row = chunk >> 3, slot = chunk & 7;
            const int4 v = *(const int4*)(Mb + (size_t)(j0 + row)*DD + kc + slot*8);
            *(int4*)(ms + row*GBK + ((slot ^ (row & 7)) * 8)) = v;
        }
        __syncthreads();

        #pragma unroll
        for (int kk = 0; kk < 2; ++kk) {
            bf16x8 av[4], bv[2];
            #pragma unroll
            for (int mt = 0; mt < 4; ++mt) {
                const int row  = 64*wm + 16*mt + ln;
                const int slot = (4*kk + lg) ^ (row & 7);
                av[mt] = *(const bf16x8*)(xs + row*GBK + slot*8);
            }
            #pragma unroll
            for (int nt = 0; nt < 2; ++nt) {
                const int row  = 32*wn + 16*nt + ln;
                const int slot = (4*kk + lg) ^ (row & 7);
                bv[nt] = *(const bf16x8*)(ms + row*GBK + slot*8);
            }
            #pragma unroll
            for (int mt = 0; mt < 4; ++mt)
                #pragma unroll
                for (int nt = 0; nt < 2; ++nt)
                    acc[mt][nt] = __builtin_amdgcn_mfma_f32_16x16x32_bf16(
                        av[mt], bv[nt], acc[mt][nt], 0, 0, 0);
        }
        __syncthreads();
    }

    // C/D layout: col=lane&15, row=(lane>>4)*4+reg  [m89/m91]
    float c3v[2];
    #pragma unroll
    for (int nt = 0; nt < 2; ++nt) c3v[nt] = c3[j0 + 32*wn + 16*nt + ln];

    #pragma unroll
    for (int mt = 0; mt < 4; ++mt)
        #pragma unroll
        for (int nt = 0; nt < 2; ++nt) {
            const int j = j0 + 32*wn + 16*nt + ln;
            #pragma unroll
            for (int r = 0; r < 4; ++r) {
                const int b = b0 + 64*wm + 16*mt + 4*lg + r;
                out[(size_t)b*JJ + j] = acc[mt][nt][r] + c3v[nt];
            }
        }
}

// ---------------------------------------------------------------------------
extern "C" void kernel_launch(void* const* d_in, const int* in_sizes, int n_in,
                              void* d_out, int out_size, void* d_ws, size_t ws_size,
                              hipStream_t stream)
{
    const float* x  = (const float*)d_in[0];
    const float* W1 = (const float*)d_in[1];
    const float* b1 = (const float*)d_in[2];
    const float* W2 = (const float*)d_in[3];
    const float* b2 = (const float*)d_in[4];
    const float* Wv = (const float*)d_in[5];
    const float* bv = (const float*)d_in[6];
    const float* Wa = (const float*)d_in[7];
    const float* ba = (const float*)d_in[8];
    float* out = (float*)d_out;
    float* ws  = (float*)d_ws;

    // workspace: Vsum[JD] f32 | c3[JJ] f32 | Xb[BB*DD] bf16 | Mb[JD] bf16
    float* Vsum = ws;
    float* c3   = Vsum + JD;
    unsigned short* Xb = (unsigned short*)(c3 + JJ);
    unsigned short* Mb = Xb + (size_t)BB*DD;

    k_convX<<<dim3(BB*DD/4/256), 256, 0, stream>>>(x, Xb);
    k_V    <<<dim3(16, NH), 256, 0, stream>>>(W2, Wv, Wa, Vsum);
    k_M    <<<dim3(16, NH), 256, 0, stream>>>(W1, Vsum, Mb);
    k_bias <<<dim3(JJ), 64, 0, stream>>>(Wv, Wa, b1, b2, bv, ba, Vsum, c3);
    k_gemm <<<dim3(BB/GBM, JJ/GBN), 256, 0, stream>>>(Xb, Mb, c3, out);
}

// Round 5
// 45.128 us; speedup vs baseline: 2.7604x; 1.1638x over previous
//
#include <hip/hip_runtime.h>
#include <hip/hip_bf16.h>

#define DD   512
#define NH   32
#define AA   18
#define JJ   (NH*AA)          // 576
#define BB   4096
#define JD   (JJ*DD)          // 294912

typedef short bf16x8 __attribute__((ext_vector_type(8)));
typedef float f32x4  __attribute__((ext_vector_type(4)));

static __device__ inline unsigned short f2bf(float f) {
    unsigned int x = __float_as_uint(f);
    unsigned int r = (x + 0x7fffu + ((x >> 16) & 1u)) >> 16;   // RNE
    return (unsigned short)r;
}

// ---------------------------------------------------------------------------
// K1: [fused]  a) convert a private 4096-float slice of x -> bf16
//              b) Vsum[n*18+a, d] = sum_e U[n,a,e] * W2[n,e,d]   (R4 core)
//              c) dc==0 blocks: c1[j] = sum_e U[j,e]*b2[n,e]
//     grid (16 d-chunks x 32 heads) = 512 blocks, 256 thr, LDS 54.3 KB.
// ---------------------------------------------------------------------------
__global__ __launch_bounds__(256) void k_V(
    const float* __restrict__ x, unsigned short* __restrict__ Xb,
    const float* __restrict__ W2, const float* __restrict__ Wv,
    const float* __restrict__ Wa, const float* __restrict__ b2,
    float* __restrict__ Vsum, float* __restrict__ c1)
{
    const int t  = threadIdx.x;
    const int dc = blockIdx.x;          // 0..15
    const int n  = blockIdx.y;          // 0..31

    __shared__ __align__(16) float us[AA * DD];       // 36 KB  [a][e]
    __shared__ __align__(16) float red[8 * AA * 32];  // 18 KB  [eg][a][dl]
    __shared__ float redc[AA * 4];                    // 288 B

    // --- a) convX slice: block bid owns float4s [bid*1024, bid*1024+1024)
    {
        const int bid = n*16 + dc;
        const float4* xin = (const float4*)x + (size_t)bid*1024;
        ushort4*      xo  = (ushort4*)Xb + (size_t)bid*1024;
        #pragma unroll
        for (int i = 0; i < 4; ++i) {
            const float4 v = xin[t + 256*i];
            ushort4 o;
            o.x = f2bf(v.x); o.y = f2bf(v.y); o.z = f2bf(v.z); o.w = f2bf(v.w);
            xo[t + 256*i] = o;
        }
    }

    // --- b) stage U (R4-validated)
    for (int el = t; el < DD; el += 256) {
        float wa[AA]; float msum = 0.f;
        #pragma unroll
        for (int a = 0; a < AA; ++a) {
            wa[a] = Wa[(size_t)(n*AA + a)*DD + el];
            msum += wa[a];
        }
        msum *= (1.0f / 18.0f);
        const float wv = Wv[(size_t)n*DD + el];
        #pragma unroll
        for (int a = 0; a < AA; ++a) us[a*DD + el] = wv + wa[a] - msum;
    }
    __syncthreads();

    const int dl = t & 31, eg = t >> 5;          // eg 0..7
    const int d  = dc*32 + dl;
    const float* w2p = W2 + (size_t)n*DD*DD + (size_t)(eg*64)*DD + d;

    float acc[AA] = {};
    for (int e8 = 0; e8 < 8; ++e8) {
        float w[8];
        #pragma unroll
        for (int j = 0; j < 8; ++j) w[j] = w2p[(size_t)(e8*8 + j)*DD];
        const int eo = eg*64 + e8*8;
        #pragma unroll
        for (int a = 0; a < AA; ++a) {
            const float4 u0 = *(const float4*)(us + a*DD + eo);
            const float4 u1 = *(const float4*)(us + a*DD + eo + 4);
            acc[a] += u0.x*w[0] + u0.y*w[1] + u0.z*w[2] + u0.w*w[3]
                    + u1.x*w[4] + u1.y*w[5] + u1.z*w[6] + u1.w*w[7];
        }
    }

    #pragma unroll
    for (int a = 0; a < AA; ++a) red[(eg*AA + a)*32 + dl] = acc[a];
    __syncthreads();

    for (int idx = t; idx < AA*32; idx += 256) {
        const int a = idx >> 5, d2 = idx & 31;
        float v = 0.f;
        #pragma unroll
        for (int g = 0; g < 8; ++g) v += red[(g*AA + a)*32 + d2];
        Vsum[(size_t)(n*AA + a)*DD + dc*32 + d2] = v;
    }

    // --- c) c1 on dc==0 blocks (us still valid; redc disjoint from red)
    if (dc == 0) {
        float p[AA];
        const float b2a = b2[(size_t)n*DD + t];
        const float b2b = b2[(size_t)n*DD + t + 256];
        #pragma unroll
        for (int a = 0; a < AA; ++a)
            p[a] = us[a*DD + t]*b2a + us[a*DD + t + 256]*b2b;
        #pragma unroll
        for (int a = 0; a < AA; ++a)
            for (int o = 32; o; o >>= 1) p[a] += __shfl_xor(p[a], o, 64);
        if ((t & 63) == 0) {
            const int w = t >> 6;
            #pragma unroll
            for (int a = 0; a < AA; ++a) redc[a*4 + w] = p[a];
        }
        __syncthreads();
        if (t < AA)
            c1[n*AA + t] = redc[t*4] + redc[t*4+1] + redc[t*4+2] + redc[t*4+3];
    }
}

// ---------------------------------------------------------------------------
// K2: [fused]  a) M[n*18+a, k] = sum_d Vsum[...]*W1[...] -> bf16  (R4 core)
//              b) kc==0 blocks: c3[j] = c1[j] + sum_d Vsum[j,d]*b1[n,d]
//                               + bv[n] + ba[j] - mean_a(ba[n,:])
// ---------------------------------------------------------------------------
__global__ __launch_bounds__(256) void k_M(
    const float* __restrict__ W1, const float* __restrict__ Vsum,
    const float* __restrict__ b1, const float* __restrict__ bv,
    const float* __restrict__ ba, const float* __restrict__ c1,
    unsigned short* __restrict__ Mb, float* __restrict__ c3)
{
    const int t  = threadIdx.x;
    const int kc = blockIdx.x;          // 0..15
    const int n  = blockIdx.y;          // 0..31

    __shared__ __align__(16) float vs[AA * DD];       // 36 KB
    __shared__ __align__(16) float red[8 * AA * 32];  // 18 KB
    __shared__ float redc[AA * 4];

    for (int i = t; i < AA*DD/4; i += 256)
        ((float4*)vs)[i] = ((const float4*)(Vsum + (size_t)n*AA*DD))[i];
    __syncthreads();

    const int kl = t & 31, dg = t >> 5;
    const int k  = kc*32 + kl;
    const float* w1p = W1 + ((size_t)(n*DD + dg*64))*DD + k;

    float acc[AA] = {};
    for (int d8 = 0; d8 < 8; ++d8) {
        float w[8];
        #pragma unroll
        for (int j = 0; j < 8; ++j) w[j] = w1p[(size_t)(d8*8 + j)*DD];
        const int doff = dg*64 + d8*8;
        #pragma unroll
        for (int a = 0; a < AA; ++a) {
            const float4 v0 = *(const float4*)(vs + a*DD + doff);
            const float4 v1 = *(const float4*)(vs + a*DD + doff + 4);
            acc[a] += v0.x*w[0] + v0.y*w[1] + v0.z*w[2] + v0.w*w[3]
                    + v1.x*w[4] + v1.y*w[5] + v1.z*w[6] + v1.w*w[7];
        }
    }

    #pragma unroll
    for (int a = 0; a < AA; ++a) red[(dg*AA + a)*32 + kl] = acc[a];
    __syncthreads();

    for (int idx = t; idx < AA*32; idx += 256) {
        const int a = idx >> 5, k2 = idx & 31;
        float v = 0.f;
        #pragma unroll
        for (int g = 0; g < 8; ++g) v += red[(g*AA + a)*32 + k2];
        Mb[(size_t)(n*AA + a)*DD + kc*32 + k2] = f2bf(v);
    }

    // --- b) c3 on kc==0 blocks (vs still valid)
    if (kc == 0) {
        float p[AA];
        const float b1a = b1[(size_t)n*DD + t];
        const float b1b = b1[(size_t)n*DD + t + 256];
        #pragma unroll
        for (int a = 0; a < AA; ++a)
            p[a] = vs[a*DD + t]*b1a + vs[a*DD + t + 256]*b1b;
        #pragma unroll
        for (int a = 0; a < AA; ++a)
            for (int o = 32; o; o >>= 1) p[a] += __shfl_xor(p[a], o, 64);
        if ((t & 63) == 0) {
            const int w = t >> 6;
            #pragma unroll
            for (int a = 0; a < AA; ++a) redc[a*4 + w] = p[a];
        }
        __syncthreads();
        if (t < AA) {
            float bam = 0.f;
            #pragma unroll
            for (int a = 0; a < AA; ++a) bam += ba[n*AA + a];
            c3[n*AA + t] = c1[n*AA + t]
                         + redc[t*4] + redc[t*4+1] + redc[t*4+2] + redc[t*4+3]
                         + bv[n] + ba[n*AA + t] - bam * (1.0f/18.0f);
        }
    }
}

// ---------------------------------------------------------------------------
// K3: out[b,j] = sum_k Xb[b,k]*Mb[j,k] + c3[j]   (bf16 MFMA)
//     EXACT R2/R4-validated kernel: BM=128 BN=64 BK=64, 4 waves,
//     XOR-swizzled LDS (SQ_LDS_BANK_CONFLICT == 0 measured).
// ---------------------------------------------------------------------------
#define GBM 128
#define GBN 64
#define GBK 64

__global__ __launch_bounds__(256) void k_gemm(
    const unsigned short* __restrict__ Xb,   // [4096][512] bf16 bits
    const unsigned short* __restrict__ Mb,   // [576][512]  bf16 bits
    const float* __restrict__ c3, float* __restrict__ out)
{
    __shared__ __align__(16) unsigned short xs[GBM * GBK];   // 16 KB
    __shared__ __align__(16) unsigned short ms[GBN * GBK];   //  8 KB

    const int t    = threadIdx.x;
    const int w    = t >> 6;
    const int lane = t & 63;
    const int ln   = lane & 15, lg = lane >> 4;
    const int wm   = w >> 1,   wn = w & 1;
    const int b0 = blockIdx.x * GBM;
    const int j0 = blockIdx.y * GBN;

    f32x4 acc[4][2] = {};

    for (int kc = 0; kc < DD; kc += GBK) {
        #pragma unroll
        for (int it = 0; it < 4; ++it) {
            const int chunk = it*256 + t;
            const int row = chunk >> 3, slot = chunk & 7;
            const int4 v = *(const int4*)(Xb + (size_t)(b0 + row)*DD + kc + slot*8);
            *(int4*)(xs + row*GBK + ((slot ^ (row & 7)) * 8)) = v;
        }
        #pragma unroll
        for (int it = 0; it < 2; ++it) {
            const int chunk = it*256 + t;
            const int row = chunk >> 3, slot = chunk & 7;
            const int4 v = *(const int4*)(Mb + (size_t)(j0 + row)*DD + kc + slot*8);
            *(int4*)(ms + row*GBK + ((slot ^ (row & 7)) * 8)) = v;
        }
        __syncthreads();

        #pragma unroll
        for (int kk = 0; kk < 2; ++kk) {
            bf16x8 av[4], bv[2];
            #pragma unroll
            for (int mt = 0; mt < 4; ++mt) {
                const int row  = 64*wm + 16*mt + ln;
                const int slot = (4*kk + lg) ^ (row & 7);
                av[mt] = *(const bf16x8*)(xs + row*GBK + slot*8);
            }
            #pragma unroll
            for (int nt = 0; nt < 2; ++nt) {
                const int row  = 32*wn + 16*nt + ln;
                const int slot = (4*kk + lg) ^ (row & 7);
                bv[nt] = *(const bf16x8*)(ms + row*GBK + slot*8);
            }
            #pragma unroll
            for (int mt = 0; mt < 4; ++mt)
                #pragma unroll
                for (int nt = 0; nt < 2; ++nt)
                    acc[mt][nt] = __builtin_amdgcn_mfma_f32_16x16x32_bf16(
                        av[mt], bv[nt], acc[mt][nt], 0, 0, 0);
        }
        __syncthreads();
    }

    // C/D layout: col=lane&15, row=(lane>>4)*4+reg  [m89/m91]
    float c3v[2];
    #pragma unroll
    for (int nt = 0; nt < 2; ++nt) c3v[nt] = c3[j0 + 32*wn + 16*nt + ln];

    #pragma unroll
    for (int mt = 0; mt < 4; ++mt)
        #pragma unroll
        for (int nt = 0; nt < 2; ++nt) {
            const int j = j0 + 32*wn + 16*nt + ln;
            #pragma unroll
            for (int r = 0; r < 4; ++r) {
                const int b = b0 + 64*wm + 16*mt + 4*lg + r;
                out[(size_t)b*JJ + j] = acc[mt][nt][r] + c3v[nt];
            }
        }
}

// ---------------------------------------------------------------------------
extern "C" void kernel_launch(void* const* d_in, const int* in_sizes, int n_in,
                              void* d_out, int out_size, void* d_ws, size_t ws_size,
                              hipStream_t stream)
{
    const float* x  = (const float*)d_in[0];
    const float* W1 = (const float*)d_in[1];
    const float* b1 = (const float*)d_in[2];
    const float* W2 = (const float*)d_in[3];
    const float* b2 = (const float*)d_in[4];
    const float* Wv = (const float*)d_in[5];
    const float* bv = (const float*)d_in[6];
    const float* Wa = (const float*)d_in[7];
    const float* ba = (const float*)d_in[8];
    float* out = (float*)d_out;
    float* ws  = (float*)d_ws;

    // workspace: Vsum[JD] f32 | c1[JJ] | c3[JJ] | Xb[BB*DD] bf16 | Mb[JD] bf16
    float* Vsum = ws;
    float* c1   = Vsum + JD;
    float* c3   = c1 + JJ;
    unsigned short* Xb = (unsigned short*)(c3 + JJ);
    unsigned short* Mb = Xb + (size_t)BB*DD;

    k_V   <<<dim3(16, NH), 256, 0, stream>>>(x, Xb, W2, Wv, Wa, b2, Vsum, c1);
    k_M   <<<dim3(16, NH), 256, 0, stream>>>(W1, Vsum, b1, bv, ba, c1, Mb, c3);
    k_gemm<<<dim3(BB/GBM, JJ/GBN), 256, 0, stream>>>(Xb, Mb, c3, out);
}